// Round 1
// baseline (147.362 us; speedup 1.0000x reference)
//
#include <hip/hip_runtime.h>
#include <stdint.h>

#define HW 4096
#define CH 256
#define NB 4

typedef __attribute__((ext_vector_type(8))) short bf16x8;
typedef __attribute__((ext_vector_type(4))) float f32x4;

__device__ __forceinline__ ushort f2bf(float f) {
    uint32_t u = __float_as_uint(f);
    u += 0x7fffu + ((u >> 16) & 1u);   // RNE
    return (ushort)(u >> 16);
}
__device__ __forceinline__ float bf2f(ushort h) {
    return __uint_as_float(((uint32_t)h) << 16);
}

// ---------------------------------------------------------------------------
// prep: convert 3 weight matrices fp32->bf16, zero M1 accumulator
__global__ __launch_bounds__(256) void prep_kernel(
    const float* __restrict__ Wq, const float* __restrict__ Wk,
    const float* __restrict__ Wv,
    ushort* __restrict__ Wq16, ushort* __restrict__ Wk16,
    ushort* __restrict__ Wv16, unsigned int* __restrict__ M1) {
    int i = blockIdx.x * 256 + threadIdx.x;   // grid covers 65536
    Wq16[i] = f2bf(Wq[i]);
    Wk16[i] = f2bf(Wk[i]);
    Wv16[i] = f2bf(Wv[i]);
    if (i < NB * HW) M1[i] = 0;               // soft > 0, so 0 == -inf here
}

// ---------------------------------------------------------------------------
// transpose + convert: fuse[b][c][hw] f32 -> fT[b][hw][c] bf16
__global__ __launch_bounds__(256) void transpose_kernel(
    const float* __restrict__ fuse, ushort* __restrict__ fT) {
    __shared__ float tile[32][65];
    const int b = blockIdx.z, c0 = blockIdx.y * 32, hw0 = blockIdx.x * 64;
    const int t = threadIdx.x;
    {
        const int i0 = t >> 4;
        const int j4 = (t & 15) * 4;
        const float* src = fuse + ((size_t)b * CH + c0) * HW + hw0;
        #pragma unroll
        for (int ii = 0; ii < 2; ++ii) {
            int i = i0 + ii * 16;
            float4 v = *(const float4*)(src + (size_t)i * HW + j4);
            tile[i][j4 + 0] = v.x; tile[i][j4 + 1] = v.y;
            tile[i][j4 + 2] = v.z; tile[i][j4 + 3] = v.w;
        }
    }
    __syncthreads();
    {
        const int j = t >> 2;
        const int i8 = (t & 3) * 8;
        __align__(16) ushort o8[8];
        #pragma unroll
        for (int k = 0; k < 8; ++k) o8[k] = f2bf(tile[i8 + k][j]);
        *(int4*)(fT + ((size_t)b * HW + hw0 + j) * CH + c0 + i8) = *(const int4*)o8;
    }
}

// ---------------------------------------------------------------------------
// conv1x1 GEMM: rows = out-channel o (A = W16[o][c]), cols = hw (B = fT[hw][c])
// MODE 0: write bf16 [b][hw][o] (Q or K).  MODE 1: V + mask epilogue -> f32 out.
template<int MODE>
__global__ __launch_bounds__(256) void conv_gemm_kernel(
    const ushort* __restrict__ fT, const ushort* __restrict__ W16,
    const float* __restrict__ bias,
    ushort* __restrict__ outb, float* __restrict__ outf,
    const float* __restrict__ m2v, const float* __restrict__ qmask) {
    __shared__ __align__(16) ushort Als[256][72];
    __shared__ __align__(16) ushort Bls[64][72];
    const int t = threadIdx.x;
    const int lane = t & 63, w = t >> 6;
    const int hw0 = blockIdx.x * 64;
    const int b = blockIdx.y;
    f32x4 acc[4][4] = {};   // [rf(o)][cf(hw)]
    for (int kc = 0; kc < 4; ++kc) {
        __syncthreads();
        #pragma unroll
        for (int i = 0; i < 8; ++i) {
            int q = t + 256 * i;
            int row = q >> 3, c8 = (q & 7) * 8;
            *(int4*)&Als[row][c8] =
                *(const int4*)(W16 + (size_t)row * CH + kc * 64 + c8);
        }
        #pragma unroll
        for (int i = 0; i < 2; ++i) {
            int q = t + 256 * i;
            int row = q >> 3, c8 = (q & 7) * 8;
            *(int4*)&Bls[row][c8] =
                *(const int4*)(fT + ((size_t)b * HW + hw0 + row) * CH + kc * 64 + c8);
        }
        __syncthreads();
        #pragma unroll
        for (int kk = 0; kk < 2; ++kk) {
            bf16x8 af[4];
            #pragma unroll
            for (int rf = 0; rf < 4; ++rf)
                af[rf] = *(const bf16x8*)&Als[w * 64 + rf * 16 + (lane & 15)]
                                             [kk * 32 + (lane >> 4) * 8];
            #pragma unroll
            for (int cf = 0; cf < 4; ++cf) {
                bf16x8 bf_ = *(const bf16x8*)&Bls[cf * 16 + (lane & 15)]
                                                 [kk * 32 + (lane >> 4) * 8];
                #pragma unroll
                for (int rf = 0; rf < 4; ++rf)
                    acc[rf][cf] = __builtin_amdgcn_mfma_f32_16x16x32_bf16(
                        af[rf], bf_, acc[rf][cf], 0, 0, 0);
            }
        }
    }
    #pragma unroll
    for (int rf = 0; rf < 4; ++rf) {
        const int ob = w * 64 + rf * 16 + (lane >> 4) * 4;  // o base (mult of 4)
        #pragma unroll
        for (int cf = 0; cf < 4; ++cf) {
            const int hw = hw0 + cf * 16 + (lane & 15);
            if (MODE == 0) {
                ushort4 v;
                v.x = f2bf(acc[rf][cf][0] + bias[ob + 0]);
                v.y = f2bf(acc[rf][cf][1] + bias[ob + 1]);
                v.z = f2bf(acc[rf][cf][2] + bias[ob + 2]);
                v.w = f2bf(acc[rf][cf][3] + bias[ob + 3]);
                *(ushort4*)&outb[((size_t)b * HW + hw) * CH + ob] = v;
            } else {
                const float mv = m2v[b * 64 + (ob >> 2)];
                #pragma unroll
                for (int r = 0; r < 4; ++r) {   // o = ob+r, o%4 == r
                    float vv = acc[rf][cf][r] + bias[ob + r];
                    float qm = qmask[r * HW + hw];
                    outf[((size_t)b * CH + ob + r) * HW + hw] = vv * (1.0f + mv * qm);
                }
            }
        }
    }
}

// ---------------------------------------------------------------------------
// Q_mask[(c%4)*HW + hw] = max over b, c/4 of Q[b][hw][c]
__global__ __launch_bounds__(256) void qmask_kernel(
    const ushort* __restrict__ Qw, float* __restrict__ Qmask) {
    const int t = threadIdx.x;
    const int j = t >> 5;        // 8 hw rows per block
    const int l5 = t & 31;
    const int hw = blockIdx.x * 8 + j;
    float mx = -3.4e38f;
    for (int b = 0; b < 4; ++b) {
        const ushort* rb = Qw + ((size_t)b * HW + hw) * CH;
        #pragma unroll
        for (int k = 0; k < 8; ++k) mx = fmaxf(mx, bf2f(rb[l5 + 32 * k]));
    }
    // reduce within 32-lane group over o bits 2..4 (keeps class o%4 == t&3)
    mx = fmaxf(mx, __shfl_xor(mx, 4));
    mx = fmaxf(mx, __shfl_xor(mx, 8));
    mx = fmaxf(mx, __shfl_xor(mx, 16));
    if (l5 < 4) Qmask[l5 * HW + hw] = mx;
}

// ---------------------------------------------------------------------------
// scores + batch-softmax + max-over-n reduction.
// Tile: 64 n x 64 m, all 4 batches accumulated per lane -> softmax lane-local.
__global__ __launch_bounds__(256) void scores_kernel(
    const ushort* __restrict__ Qw, const ushort* __restrict__ Kw,
    unsigned int* __restrict__ M1) {
    __shared__ __align__(16) ushort qs[4][64][72];
    __shared__ __align__(16) ushort ks2[4][64][72];
    const int t = threadIdx.x;
    const int lane = t & 63, w = t >> 6;
    const int m0 = blockIdx.x * 64, n0 = blockIdx.y * 64;
    f32x4 acc[4][4] = {};   // [b][mf]
    for (int kc = 0; kc < 4; ++kc) {
        __syncthreads();
        #pragma unroll
        for (int i = 0; i < 8; ++i) {
            int q = t + 256 * i;
            int row = q >> 3, c8 = (q & 7) * 8;
            int b = row >> 6, n = row & 63;
            *(int4*)&qs[b][n][c8] =
                *(const int4*)(Qw + (((size_t)b * HW) + n0 + n) * CH + kc * 64 + c8);
            *(int4*)&ks2[b][n][c8] =
                *(const int4*)(Kw + (((size_t)b * HW) + m0 + n) * CH + kc * 64 + c8);
        }
        __syncthreads();
        #pragma unroll
        for (int b = 0; b < 4; ++b) {
            #pragma unroll
            for (int kk = 0; kk < 2; ++kk) {
                bf16x8 a = *(const bf16x8*)&qs[b][w * 16 + (lane & 15)]
                                              [kk * 32 + (lane >> 4) * 8];
                #pragma unroll
                for (int mf = 0; mf < 4; ++mf) {
                    bf16x8 bb = *(const bf16x8*)&ks2[b][mf * 16 + (lane & 15)]
                                                    [kk * 32 + (lane >> 4) * 8];
                    acc[b][mf] = __builtin_amdgcn_mfma_f32_16x16x32_bf16(
                        a, bb, acc[b][mf], 0, 0, 0);
                }
            }
        }
    }
    const float scale = 1.0f / 16.0f;
    float pm[4][4];
    #pragma unroll
    for (int b2 = 0; b2 < 4; ++b2)
        #pragma unroll
        for (int mf = 0; mf < 4; ++mf) pm[b2][mf] = 0.0f;
    #pragma unroll
    for (int mf = 0; mf < 4; ++mf) {
        #pragma unroll
        for (int r = 0; r < 4; ++r) {
            float s0 = acc[0][mf][r] * scale;
            float s1 = acc[1][mf][r] * scale;
            float s2 = acc[2][mf][r] * scale;
            float s3 = acc[3][mf][r] * scale;
            float mx = fmaxf(fmaxf(s0, s1), fmaxf(s2, s3));
            float e0 = __expf(s0 - mx), e1 = __expf(s1 - mx);
            float e2 = __expf(s2 - mx), e3 = __expf(s3 - mx);
            float inv = 1.0f / (e0 + e1 + e2 + e3);
            pm[0][mf] = fmaxf(pm[0][mf], e0 * inv);
            pm[1][mf] = fmaxf(pm[1][mf], e1 * inv);
            pm[2][mf] = fmaxf(pm[2][mf], e2 * inv);
            pm[3][mf] = fmaxf(pm[3][mf], e3 * inv);
        }
    }
    // reduce over n within wave (lanes l, l^16, l^32, l^48 share column m)
    #pragma unroll
    for (int b2 = 0; b2 < 4; ++b2)
        #pragma unroll
        for (int mf = 0; mf < 4; ++mf) {
            float v = pm[b2][mf];
            v = fmaxf(v, __shfl_xor(v, 16));
            v = fmaxf(v, __shfl_xor(v, 32));
            pm[b2][mf] = v;
        }
    __syncthreads();   // all waves done reading qs; reuse it as reduction buf
    typedef float red_row[4][64];
    red_row* red = (red_row*)&qs[0][0][0];
    if ((lane >> 4) == 0) {
        #pragma unroll
        for (int b2 = 0; b2 < 4; ++b2)
            #pragma unroll
            for (int mf = 0; mf < 4; ++mf)
                red[w][b2][mf * 16 + lane] = pm[b2][mf];
    }
    __syncthreads();
    {
        int b2 = t >> 6, ml = t & 63;
        float v = fmaxf(fmaxf(red[0][b2][ml], red[1][b2][ml]),
                        fmaxf(red[2][b2][ml], red[3][b2][ml]));
        atomicMax(&M1[b2 * HW + m0 + ml], __float_as_uint(v));  // positive floats
    }
}

// ---------------------------------------------------------------------------
// m2[b*64+hk] = max over wk of M1[b][hk*64+wk]
__global__ __launch_bounds__(256) void m2_kernel(
    const float* __restrict__ M1f, float* __restrict__ m2) {
    const int t = threadIdx.x;
    float mx = 0.0f;
    #pragma unroll
    for (int k = 0; k < 64; k += 4) {
        float4 v = *(const float4*)(M1f + t * 64 + k);
        mx = fmaxf(mx, fmaxf(fmaxf(v.x, v.y), fmaxf(v.z, v.w)));
    }
    m2[t] = mx;
}

// ---------------------------------------------------------------------------
extern "C" void kernel_launch(void* const* d_in, const int* in_sizes, int n_in,
                              void* d_out, int out_size, void* d_ws, size_t ws_size,
                              hipStream_t stream) {
    const float* fuse = (const float*)d_in[0];
    const float* Wq   = (const float*)d_in[1];
    const float* bq   = (const float*)d_in[2];
    const float* Wk   = (const float*)d_in[3];
    const float* bk   = (const float*)d_in[4];
    const float* Wv   = (const float*)d_in[5];
    const float* bv   = (const float*)d_in[6];
    float* out = (float*)d_out;

    char* ws = (char*)d_ws;
    // ws layout (total ~24.5 MiB)
    ushort* fT    = (ushort*)(ws);                            // 8 MiB
    ushort* Wq16  = (ushort*)(ws + 8388608);                  // 128 KiB
    ushort* Wk16  = (ushort*)(ws + 8388608 + 131072);         // 128 KiB
    ushort* Wv16  = (ushort*)(ws + 8388608 + 262144);         // 128 KiB
    ushort* Qw    = (ushort*)(ws + 8388608 + 393216);         // 8 MiB
    ushort* Kw    = (ushort*)(ws + 16777216 + 393216);        // 8 MiB
    float*  Qmask = (float*) (ws + 25165824 + 393216);        // 64 KiB
    unsigned int* M1 = (unsigned int*)(ws + 25165824 + 458752); // 64 KiB
    float*  m2    = (float*) (ws + 25165824 + 524288);        // 1 KiB

    prep_kernel<<<256, 256, 0, stream>>>(Wq, Wk, Wv, Wq16, Wk16, Wv16, M1);
    transpose_kernel<<<dim3(64, 8, NB), 256, 0, stream>>>(fuse, fT);
    conv_gemm_kernel<0><<<dim3(64, NB), 256, 0, stream>>>(
        fT, Wq16, bq, Qw, nullptr, nullptr, nullptr);
    conv_gemm_kernel<0><<<dim3(64, NB), 256, 0, stream>>>(
        fT, Wk16, bk, Kw, nullptr, nullptr, nullptr);
    qmask_kernel<<<512, 256, 0, stream>>>(Qw, Qmask);
    scores_kernel<<<dim3(64, 64), 256, 0, stream>>>(Qw, Kw, M1);
    m2_kernel<<<1, 256, 0, stream>>>((const float*)M1, m2);
    conv_gemm_kernel<1><<<dim3(64, NB), 256, 0, stream>>>(
        fT, Wv16, bv, nullptr, out, m2, Qmask);
}

// Round 2
// 136.311 us; speedup vs baseline: 1.0811x; 1.0811x over previous
//
#include <hip/hip_runtime.h>
#include <stdint.h>

#define HW 4096
#define CH 256
#define NB 4

typedef __attribute__((ext_vector_type(8))) short bf16x8;
typedef __attribute__((ext_vector_type(4))) float f32x4;

__device__ __forceinline__ ushort f2bf(float f) {
    uint32_t u = __float_as_uint(f);
    u += 0x7fffu + ((u >> 16) & 1u);   // RNE
    return (ushort)(u >> 16);
}
__device__ __forceinline__ float bf2f(ushort h) {
    return __uint_as_float(((uint32_t)h) << 16);
}

#define GLOAD_LDS16(g, l) __builtin_amdgcn_global_load_lds(                    \
    (const __attribute__((address_space(1))) uint32_t*)(g),                    \
    (__attribute__((address_space(3))) uint32_t*)(l), 16, 0, 0)

// ---------------------------------------------------------------------------
// prep: convert 3 weight matrices fp32->bf16, zero M1 accumulator
__global__ __launch_bounds__(256) void prep_kernel(
    const float* __restrict__ Wq, const float* __restrict__ Wk,
    const float* __restrict__ Wv,
    ushort* __restrict__ Wq16, ushort* __restrict__ Wk16,
    ushort* __restrict__ Wv16, unsigned int* __restrict__ M1) {
    int i = blockIdx.x * 256 + threadIdx.x;   // grid covers 65536
    Wq16[i] = f2bf(Wq[i]);
    Wk16[i] = f2bf(Wk[i]);
    Wv16[i] = f2bf(Wv[i]);
    if (i < NB * HW) M1[i] = 0;               // soft > 0, so 0 == -inf here
}

// ---------------------------------------------------------------------------
// transpose + convert: fuse[b][c][hw] f32 -> fT[b][hw][c] bf16
__global__ __launch_bounds__(256) void transpose_kernel(
    const float* __restrict__ fuse, ushort* __restrict__ fT) {
    __shared__ float tile[32][65];
    const int b = blockIdx.z, c0 = blockIdx.y * 32, hw0 = blockIdx.x * 64;
    const int t = threadIdx.x;
    {
        const int i0 = t >> 4;
        const int j4 = (t & 15) * 4;
        const float* src = fuse + ((size_t)b * CH + c0) * HW + hw0;
        #pragma unroll
        for (int ii = 0; ii < 2; ++ii) {
            int i = i0 + ii * 16;
            float4 v = *(const float4*)(src + (size_t)i * HW + j4);
            tile[i][j4 + 0] = v.x; tile[i][j4 + 1] = v.y;
            tile[i][j4 + 2] = v.z; tile[i][j4 + 3] = v.w;
        }
    }
    __syncthreads();
    {
        const int j = t >> 2;
        const int i8 = (t & 3) * 8;
        __align__(16) ushort o8[8];
        #pragma unroll
        for (int k = 0; k < 8; ++k) o8[k] = f2bf(tile[i8 + k][j]);
        *(int4*)(fT + ((size_t)b * HW + hw0 + j) * CH + c0 + i8) = *(const int4*)o8;
    }
}

// ---------------------------------------------------------------------------
// conv1x1 GEMM: rows = out-channel o (A = W16[o][c]), cols = hw (B = fT[hw][c])
// MODE 0: write bf16 [b][hw][o] (Q or K).  MODE 1: V + mask epilogue -> f32 out.
template<int MODE>
__global__ __launch_bounds__(256) void conv_gemm_kernel(
    const ushort* __restrict__ fT, const ushort* __restrict__ W16,
    const float* __restrict__ bias,
    ushort* __restrict__ outb, float* __restrict__ outf,
    const float* __restrict__ m2v, const float* __restrict__ qmask) {
    __shared__ __align__(16) ushort Als[256][72];
    __shared__ __align__(16) ushort Bls[64][72];
    const int t = threadIdx.x;
    const int lane = t & 63, w = t >> 6;
    const int hw0 = blockIdx.x * 64;
    const int b = blockIdx.y;
    f32x4 acc[4][4] = {};   // [rf(o)][cf(hw)]
    for (int kc = 0; kc < 4; ++kc) {
        __syncthreads();
        #pragma unroll
        for (int i = 0; i < 8; ++i) {
            int q = t + 256 * i;
            int row = q >> 3, c8 = (q & 7) * 8;
            *(int4*)&Als[row][c8] =
                *(const int4*)(W16 + (size_t)row * CH + kc * 64 + c8);
        }
        #pragma unroll
        for (int i = 0; i < 2; ++i) {
            int q = t + 256 * i;
            int row = q >> 3, c8 = (q & 7) * 8;
            *(int4*)&Bls[row][c8] =
                *(const int4*)(fT + ((size_t)b * HW + hw0 + row) * CH + kc * 64 + c8);
        }
        __syncthreads();
        #pragma unroll
        for (int kk = 0; kk < 2; ++kk) {
            bf16x8 af[4];
            #pragma unroll
            for (int rf = 0; rf < 4; ++rf)
                af[rf] = *(const bf16x8*)&Als[w * 64 + rf * 16 + (lane & 15)]
                                             [kk * 32 + (lane >> 4) * 8];
            #pragma unroll
            for (int cf = 0; cf < 4; ++cf) {
                bf16x8 bf_ = *(const bf16x8*)&Bls[cf * 16 + (lane & 15)]
                                                 [kk * 32 + (lane >> 4) * 8];
                #pragma unroll
                for (int rf = 0; rf < 4; ++rf)
                    acc[rf][cf] = __builtin_amdgcn_mfma_f32_16x16x32_bf16(
                        af[rf], bf_, acc[rf][cf], 0, 0, 0);
            }
        }
    }
    #pragma unroll
    for (int rf = 0; rf < 4; ++rf) {
        const int ob = w * 64 + rf * 16 + (lane >> 4) * 4;  // o base (mult of 4)
        #pragma unroll
        for (int cf = 0; cf < 4; ++cf) {
            const int hw = hw0 + cf * 16 + (lane & 15);
            if (MODE == 0) {
                ushort4 v;
                v.x = f2bf(acc[rf][cf][0] + bias[ob + 0]);
                v.y = f2bf(acc[rf][cf][1] + bias[ob + 1]);
                v.z = f2bf(acc[rf][cf][2] + bias[ob + 2]);
                v.w = f2bf(acc[rf][cf][3] + bias[ob + 3]);
                *(ushort4*)&outb[((size_t)b * HW + hw) * CH + ob] = v;
            } else {
                const float mv = m2v[b * 64 + (ob >> 2)];
                #pragma unroll
                for (int r = 0; r < 4; ++r) {   // o = ob+r, o%4 == r
                    float vv = acc[rf][cf][r] + bias[ob + r];
                    float qm = qmask[r * HW + hw];
                    outf[((size_t)b * CH + ob + r) * HW + hw] = vv * (1.0f + mv * qm);
                }
            }
        }
    }
}

// ---------------------------------------------------------------------------
// Q_mask[(c%4)*HW + hw] = max over b, c/4 of Q[b][hw][c]
__global__ __launch_bounds__(256) void qmask_kernel(
    const ushort* __restrict__ Qw, float* __restrict__ Qmask) {
    const int t = threadIdx.x;
    const int j = t >> 5;        // 8 hw rows per block
    const int l5 = t & 31;
    const int hw = blockIdx.x * 8 + j;
    float mx = -3.4e38f;
    for (int b = 0; b < 4; ++b) {
        const ushort* rb = Qw + ((size_t)b * HW + hw) * CH;
        #pragma unroll
        for (int k = 0; k < 8; ++k) mx = fmaxf(mx, bf2f(rb[l5 + 32 * k]));
    }
    // reduce within 32-lane group over o bits 2..4 (keeps class o%4 == t&3)
    mx = fmaxf(mx, __shfl_xor(mx, 4));
    mx = fmaxf(mx, __shfl_xor(mx, 8));
    mx = fmaxf(mx, __shfl_xor(mx, 16));
    if (l5 < 4) Qmask[l5 * HW + hw] = mx;
}

// ---------------------------------------------------------------------------
// scores + batch-softmax + max-over-n reduction.
// 512 threads = 8 waves: wave w -> (batch b = w&3, n-half nh = w>>2).
// Block tile: 128n x 128m, per-wave 64n x 128m of ONE batch (nf=4 x mf=8).
// Staging: global_load_lds 16B, LDS linear [4][128][32] per chunk, chunk-XOR
// swizzle (slot = c ^ ((row>>1)&3)) applied on the SOURCE address + reads.
// Double-buffered 32-ch chunks (8 chunks). Softmax via LDS score exchange.
__global__ __launch_bounds__(512, 2) void scores_kernel(
    const ushort* __restrict__ Qw, const ushort* __restrict__ Kw,
    unsigned int* __restrict__ M1) {
    __shared__ __align__(16) char pool[131072];   // 2 x (Q 32K + K 32K); epilogue reuse
    const int t = threadIdx.x;
    const int lane = t & 63, w = t >> 6;
    const int b = w & 3, nh = w >> 2;
    const int m0 = blockIdx.x * 128, n0 = blockIdx.y * 128;

    // staging source: wave w stages tile (w>>2): 0=Q rows, 1=K rows, batch w&3
    const int tile = w >> 2, wb = w & 3;
    const ushort* Src = tile ? Kw : Qw;
    const int base0 = tile ? m0 : n0;
    const int ssw = ((lane & 3) ^ ((lane >> 3) & 3)) << 3;  // src chunk swizzle (ushorts)
    const ushort* gp0 = Src + ((size_t)(wb * HW + base0 + (lane >> 2))) * CH + ssw;
    char* lp0 = pool + (tile * 512 + wb * 128) * 64;

    // read-side swizzled chunk byte offset (same for every fragment row)
    const int rsw = (((lane >> 4) ^ ((lane >> 1) & 3)) << 4);
    const int l15 = lane & 15;

    f32x4 acc[4][8] = {};   // [nf][mf]

    // prologue: stage chunk 0 into buf 0
    #pragma unroll
    for (int j = 0; j < 8; ++j)
        GLOAD_LDS16(gp0 + (size_t)(j * 16) * CH, lp0 + j * 1024);

    for (int kc = 0; kc < 8; ++kc) {
        const int cur = kc & 1;
        __syncthreads();   // drains DMA for buf[cur]; prev reads of buf[cur^1] done
        if (kc + 1 < 8) {
            const ushort* gp = gp0 + (kc + 1) * 32;
            char* lp = lp0 + (cur ^ 1) * 65536;
            #pragma unroll
            for (int j = 0; j < 8; ++j)
                GLOAD_LDS16(gp + (size_t)(j * 16) * CH, lp + j * 1024);
        }
        const char* qb = pool + cur * 65536 + (b * 128) * 64;
        const char* kb = pool + cur * 65536 + 32768 + (b * 128) * 64;
        bf16x8 af[4];
        #pragma unroll
        for (int nf = 0; nf < 4; ++nf) {
            int row = nh * 64 + nf * 16 + l15;
            af[nf] = *(const bf16x8*)(qb + row * 64 + rsw);
        }
        #pragma unroll
        for (int mf = 0; mf < 8; ++mf) {
            int row = mf * 16 + l15;
            bf16x8 bb = *(const bf16x8*)(kb + row * 64 + rsw);
            #pragma unroll
            for (int nf = 0; nf < 4; ++nf)
                acc[nf][mf] = __builtin_amdgcn_mfma_f32_16x16x32_bf16(
                    af[nf], bb, acc[nf][mf], 0, 0, 0);
        }
    }

    // ---- epilogue: exchange scores via LDS, softmax over batch, max over n ----
    // 4 steps of 32 m-cols. SC[4b][32m][132n] f32 (67.6 KiB), red at +98304.
    float* SC  = (float*)pool;
    float* red = (float*)(pool + 98304);
    #pragma unroll
    for (int s = 0; s < 4; ++s) {
        __syncthreads();   // prev step's reads (or k-loop reads) done
        #pragma unroll
        for (int mp = 0; mp < 2; ++mp) {
            const int mc = mp * 16 + l15;
            #pragma unroll
            for (int nf = 0; nf < 4; ++nf) {
                const int n = nh * 64 + nf * 16 + (lane >> 4) * 4;
                f32x4 st = acc[nf][2 * s + mp] * 0.0625f;   // 1/sqrt(C)
                *(f32x4*)&SC[(b * 32 + mc) * 132 + n] = st;
            }
        }
        __syncthreads();
        {
            const int ml = lane & 31;               // m col within step
            const int nsub = w * 2 + (lane >> 5);   // 16 groups of 8 n
            float pm[4] = {0.f, 0.f, 0.f, 0.f};
            #pragma unroll
            for (int q = 0; q < 2; ++q) {
                f32x4 sv[4];
                #pragma unroll
                for (int b2 = 0; b2 < 4; ++b2)
                    sv[b2] = *(const f32x4*)&SC[(b2 * 32 + ml) * 132 + nsub * 8 + q * 4];
                #pragma unroll
                for (int j = 0; j < 4; ++j) {
                    float s0 = sv[0][j], s1 = sv[1][j], s2 = sv[2][j], s3 = sv[3][j];
                    float mx = fmaxf(fmaxf(s0, s1), fmaxf(s2, s3));
                    float e0 = __expf(s0 - mx), e1 = __expf(s1 - mx);
                    float e2 = __expf(s2 - mx), e3 = __expf(s3 - mx);
                    float inv = 1.0f / (e0 + e1 + e2 + e3);
                    pm[0] = fmaxf(pm[0], e0 * inv); pm[1] = fmaxf(pm[1], e1 * inv);
                    pm[2] = fmaxf(pm[2], e2 * inv); pm[3] = fmaxf(pm[3], e3 * inv);
                }
            }
            #pragma unroll
            for (int b2 = 0; b2 < 4; ++b2)
                pm[b2] = fmaxf(pm[b2], __shfl_xor(pm[b2], 32));
            if (lane < 32) {
                #pragma unroll
                for (int b2 = 0; b2 < 4; ++b2)
                    red[(w * 4 + b2) * 32 + ml] = pm[b2];
            }
        }
        __syncthreads();
        if (t < 128) {
            const int b2 = t >> 5, mc = t & 31;
            float v = red[b2 * 32 + mc];
            #pragma unroll
            for (int w2 = 1; w2 < 8; ++w2)
                v = fmaxf(v, red[(w2 * 4 + b2) * 32 + mc]);
            atomicMax(&M1[b2 * HW + m0 + s * 32 + mc], __float_as_uint(v));
        }
    }
}

// ---------------------------------------------------------------------------
// m2[b*64+hk] = max over wk of M1[b][hk*64+wk]
__global__ __launch_bounds__(256) void m2_kernel(
    const float* __restrict__ M1f, float* __restrict__ m2) {
    const int t = threadIdx.x;
    float mx = 0.0f;
    #pragma unroll
    for (int k = 0; k < 64; k += 4) {
        float4 v = *(const float4*)(M1f + t * 64 + k);
        mx = fmaxf(mx, fmaxf(fmaxf(v.x, v.y), fmaxf(v.z, v.w)));
    }
    m2[t] = mx;
}

// ---------------------------------------------------------------------------
extern "C" void kernel_launch(void* const* d_in, const int* in_sizes, int n_in,
                              void* d_out, int out_size, void* d_ws, size_t ws_size,
                              hipStream_t stream) {
    const float* fuse = (const float*)d_in[0];
    const float* Wq   = (const float*)d_in[1];
    const float* bq   = (const float*)d_in[2];
    const float* Wk   = (const float*)d_in[3];
    const float* bk   = (const float*)d_in[4];
    const float* Wv   = (const float*)d_in[5];
    const float* bv   = (const float*)d_in[6];
    float* out = (float*)d_out;

    char* ws = (char*)d_ws;
    ushort* fT    = (ushort*)(ws);                            // 8 MiB
    ushort* Wq16  = (ushort*)(ws + 8388608);                  // 128 KiB
    ushort* Wk16  = (ushort*)(ws + 8388608 + 131072);         // 128 KiB
    ushort* Wv16  = (ushort*)(ws + 8388608 + 262144);         // 128 KiB
    ushort* Qw    = (ushort*)(ws + 8388608 + 393216);         // 8 MiB
    ushort* Kw    = (ushort*)(ws + 16777216 + 393216);        // 8 MiB
    float*  Qmask = (float*) (ws + 25165824 + 393216);        // 64 KiB
    unsigned int* M1 = (unsigned int*)(ws + 25165824 + 458752); // 64 KiB
    float*  m2    = (float*) (ws + 25165824 + 524288);        // 1 KiB

    prep_kernel<<<256, 256, 0, stream>>>(Wq, Wk, Wv, Wq16, Wk16, Wv16, M1);
    transpose_kernel<<<dim3(64, 8, NB), 256, 0, stream>>>(fuse, fT);
    conv_gemm_kernel<0><<<dim3(64, NB), 256, 0, stream>>>(
        fT, Wq16, bq, Qw, nullptr, nullptr, nullptr);
    conv_gemm_kernel<0><<<dim3(64, NB), 256, 0, stream>>>(
        fT, Wk16, bk, Kw, nullptr, nullptr, nullptr);
    qmask_kernel<<<512, 256, 0, stream>>>(Qw, Qmask);
    scores_kernel<<<dim3(32, 32), 512, 0, stream>>>(Qw, Kw, M1);
    m2_kernel<<<1, 256, 0, stream>>>((const float*)M1, m2);
    conv_gemm_kernel<1><<<dim3(64, NB), 256, 0, stream>>>(
        fT, Wv16, bv, nullptr, out, m2, Qmask);
}

// Round 3
// 129.962 us; speedup vs baseline: 1.1339x; 1.0489x over previous
//
#include <hip/hip_runtime.h>
#include <stdint.h>

#define HW 4096
#define CH 256
#define NB 4

typedef __attribute__((ext_vector_type(8))) short bf16x8;
typedef __attribute__((ext_vector_type(4))) float f32x4;

__device__ __forceinline__ ushort f2bf(float f) {
    uint32_t u = __float_as_uint(f);
    u += 0x7fffu + ((u >> 16) & 1u);   // RNE
    return (ushort)(u >> 16);
}
__device__ __forceinline__ float bf2f(ushort h) {
    return __uint_as_float(((uint32_t)h) << 16);
}

#define GLOAD_LDS16(g, l) __builtin_amdgcn_global_load_lds(                    \
    (const __attribute__((address_space(1))) uint32_t*)(g),                    \
    (__attribute__((address_space(3))) uint32_t*)(l), 16, 0, 0)

// ---------------------------------------------------------------------------
// prep: convert 3 weight matrices fp32->bf16, zero M1 accumulator
__global__ __launch_bounds__(256) void prep_kernel(
    const float* __restrict__ Wq, const float* __restrict__ Wk,
    const float* __restrict__ Wv,
    ushort* __restrict__ Wq16, ushort* __restrict__ Wk16,
    ushort* __restrict__ Wv16, unsigned int* __restrict__ M1) {
    int i = blockIdx.x * 256 + threadIdx.x;   // grid covers 65536
    Wq16[i] = f2bf(Wq[i]);
    Wk16[i] = f2bf(Wk[i]);
    Wv16[i] = f2bf(Wv[i]);
    if (i < NB * HW) M1[i] = 0;               // soft > 0, so 0 == -inf here
}

// ---------------------------------------------------------------------------
// transpose + convert: fuse[b][c][hw] f32 -> fT[b][hw][c] bf16
__global__ __launch_bounds__(256) void transpose_kernel(
    const float* __restrict__ fuse, ushort* __restrict__ fT) {
    __shared__ float tile[32][65];
    const int b = blockIdx.z, c0 = blockIdx.y * 32, hw0 = blockIdx.x * 64;
    const int t = threadIdx.x;
    {
        const int i0 = t >> 4;
        const int j4 = (t & 15) * 4;
        const float* src = fuse + ((size_t)b * CH + c0) * HW + hw0;
        #pragma unroll
        for (int ii = 0; ii < 2; ++ii) {
            int i = i0 + ii * 16;
            float4 v = *(const float4*)(src + (size_t)i * HW + j4);
            tile[i][j4 + 0] = v.x; tile[i][j4 + 1] = v.y;
            tile[i][j4 + 2] = v.z; tile[i][j4 + 3] = v.w;
        }
    }
    __syncthreads();
    {
        const int j = t >> 2;
        const int i8 = (t & 3) * 8;
        __align__(16) ushort o8[8];
        #pragma unroll
        for (int k = 0; k < 8; ++k) o8[k] = f2bf(tile[i8 + k][j]);
        *(int4*)(fT + ((size_t)b * HW + hw0 + j) * CH + c0 + i8) = *(const int4*)o8;
    }
}

// ---------------------------------------------------------------------------
// conv1x1 GEMM: rows = out-channel o (A = W16[o][c]), cols = hw (B = fT[hw][c])
// MODE 0: write bf16 CHANNEL-BLOCKED [b][o>>5][hw][o&31] (Q or K).
// MODE 1: V + mask epilogue (m2 computed in-kernel from M1) -> f32 out.
template<int MODE>
__global__ __launch_bounds__(256) void conv_gemm_kernel(
    const ushort* __restrict__ fT, const ushort* __restrict__ W16,
    const float* __restrict__ bias,
    ushort* __restrict__ outb, float* __restrict__ outf,
    const float* __restrict__ M1f, const float* __restrict__ qmask) {
    __shared__ __align__(16) ushort Als[256][72];
    __shared__ __align__(16) ushort Bls[64][72];
    __shared__ float m2s[64];
    const int t = threadIdx.x;
    const int lane = t & 63, w = t >> 6;
    const int hw0 = blockIdx.x * 64;
    const int b = blockIdx.y;
    if (MODE == 1) {   // fold m2: m2s[hk] = max over wk of M1[b][hk*64+wk]
        const int hk = t >> 2, q = t & 3;
        const float* rp = M1f + b * HW + hk * 64 + q * 16;
        float mx = 0.f;
        #pragma unroll
        for (int k2 = 0; k2 < 16; k2 += 4) {
            float4 v = *(const float4*)(rp + k2);
            mx = fmaxf(mx, fmaxf(fmaxf(v.x, v.y), fmaxf(v.z, v.w)));
        }
        mx = fmaxf(mx, __shfl_xor(mx, 1));
        mx = fmaxf(mx, __shfl_xor(mx, 2));
        if (q == 0) m2s[hk] = mx;
    }
    f32x4 acc[4][4] = {};   // [rf(o)][cf(hw)]
    for (int kc = 0; kc < 4; ++kc) {
        __syncthreads();
        #pragma unroll
        for (int i = 0; i < 8; ++i) {
            int q = t + 256 * i;
            int row = q >> 3, c8 = (q & 7) * 8;
            *(int4*)&Als[row][c8] =
                *(const int4*)(W16 + (size_t)row * CH + kc * 64 + c8);
        }
        #pragma unroll
        for (int i = 0; i < 2; ++i) {
            int q = t + 256 * i;
            int row = q >> 3, c8 = (q & 7) * 8;
            *(int4*)&Bls[row][c8] =
                *(const int4*)(fT + ((size_t)b * HW + hw0 + row) * CH + kc * 64 + c8);
        }
        __syncthreads();
        #pragma unroll
        for (int kk = 0; kk < 2; ++kk) {
            bf16x8 af[4];
            #pragma unroll
            for (int rf = 0; rf < 4; ++rf)
                af[rf] = *(const bf16x8*)&Als[w * 64 + rf * 16 + (lane & 15)]
                                             [kk * 32 + (lane >> 4) * 8];
            #pragma unroll
            for (int cf = 0; cf < 4; ++cf) {
                bf16x8 bf_ = *(const bf16x8*)&Bls[cf * 16 + (lane & 15)]
                                                 [kk * 32 + (lane >> 4) * 8];
                #pragma unroll
                for (int rf = 0; rf < 4; ++rf)
                    acc[rf][cf] = __builtin_amdgcn_mfma_f32_16x16x32_bf16(
                        af[rf], bf_, acc[rf][cf], 0, 0, 0);
            }
        }
    }
    #pragma unroll
    for (int rf = 0; rf < 4; ++rf) {
        const int ob = w * 64 + rf * 16 + (lane >> 4) * 4;  // o base (mult of 4)
        #pragma unroll
        for (int cf = 0; cf < 4; ++cf) {
            const int hw = hw0 + cf * 16 + (lane & 15);
            if (MODE == 0) {
                ushort4 v;
                v.x = f2bf(acc[rf][cf][0] + bias[ob + 0]);
                v.y = f2bf(acc[rf][cf][1] + bias[ob + 1]);
                v.z = f2bf(acc[rf][cf][2] + bias[ob + 2]);
                v.w = f2bf(acc[rf][cf][3] + bias[ob + 3]);
                // channel-blocked: [b][ob>>5][hw][ob&31]
                *(ushort4*)&outb[(((size_t)b * 8 + (ob >> 5)) * HW + hw) * 32
                                 + (ob & 31)] = v;
            } else {
                const float mv = m2s[ob >> 2];
                #pragma unroll
                for (int r = 0; r < 4; ++r) {   // o = ob+r, o%4 == r
                    float vv = acc[rf][cf][r] + bias[ob + r];
                    float qm = qmask[r * HW + hw];
                    outf[((size_t)b * CH + ob + r) * HW + hw] = vv * (1.0f + mv * qm);
                }
            }
        }
    }
}

// ---------------------------------------------------------------------------
// Q_mask[(c%4)*HW + hw] = max over b, c/4 of Q[b][c][hw]; Q channel-blocked.
__global__ __launch_bounds__(256) void qmask_kernel(
    const ushort* __restrict__ Qw, float* __restrict__ Qmask) {
    const int t = threadIdx.x;
    const int j = t >> 5;        // 8 hw rows per block
    const int l5 = t & 31;
    const int hw = blockIdx.x * 8 + j;
    float mx = -3.4e38f;
    for (int b = 0; b < 4; ++b) {
        #pragma unroll
        for (int k = 0; k < 8; ++k) {   // c = k*32 + l5; c&3 == l5&3
            ushort u = Qw[(((size_t)b * 8 + k) * HW + hw) * 32 + l5];
            mx = fmaxf(mx, bf2f(u));
        }
    }
    // reduce within 32-lane group over c bits 2..4 (keeps class c%4 == l5&3)
    mx = fmaxf(mx, __shfl_xor(mx, 4));
    mx = fmaxf(mx, __shfl_xor(mx, 8));
    mx = fmaxf(mx, __shfl_xor(mx, 16));
    if (l5 < 4) Qmask[l5 * HW + hw] = mx;
}

// ---------------------------------------------------------------------------
// scores + batch-softmax + max-over-n reduction.
// 512 threads = 8 waves: wave w -> (batch b = w&3, n-half nh = w>>2).
// Block tile: 128n x 128m, per-wave 64n x 128m of ONE batch (nf=4 x mf=8).
// Staging: global_load_lds 16B from channel-blocked [b][kc][hw][32] layout ->
// each wave-load is 1KB CONTIGUOUS. LDS linear [tile][b][128row][64B]; source
// 16B-permute within the 1KB mirrors the read-side XOR (R2-verified algebra).
// XCD-clustered grid swizzle: xcd owns 4 n-tiles; window = 4n x 8m (~3MB L2).
__global__ __launch_bounds__(512, 2) void scores_kernel(
    const ushort* __restrict__ Qw, const ushort* __restrict__ Kw,
    unsigned int* __restrict__ M1) {
    __shared__ __align__(16) char pool[131072];   // 2 x (Q 32K + K 32K); epilogue reuse
    const int t = threadIdx.x;
    const int lane = t & 63, w = t >> 6;
    const int b = w & 3, nh = w >> 2;
    // bijective XCD-clustered swizzle of the 32x32 tile grid
    const int id = blockIdx.y * 32 + blockIdx.x;
    const int xcd = id & 7, jj = id >> 3, wg = jj >> 5, r = jj & 31;
    const int vn = xcd * 4 + (r & 3), vm = wg * 8 + (r >> 2);
    const int m0 = vm * 128, n0 = vn * 128;

    // staging role: wave w stages tile (w>>2): 0=Q rows, 1=K rows, batch w&3
    const int tile = w >> 2, wb = w & 3;
    const ushort* Src = tile ? Kw : Qw;
    const int base0 = tile ? m0 : n0;
    const int sub = (lane & 3) ^ ((lane >> 3) & 3);  // 16B slot permutation
    // chunk kc region: ((wb*8+kc)*HW + base0) * 32 ushorts; lane covers
    // row (lane>>2) within each 16-row group, slot `sub`.
    const ushort* gp0 = Src + ((size_t)(wb * 8) * HW + base0 + (lane >> 2)) * 32
                        + sub * 8;
    char* lp0 = pool + (tile * 512 + wb * 128) * 64;

    // read-side swizzled chunk byte offset (same for every fragment row)
    const int rsw = (((lane >> 4) ^ ((lane >> 1) & 3)) << 4);
    const int l15 = lane & 15;

    f32x4 acc[4][8] = {};   // [nf][mf]

    // prologue: stage chunk 0 into buf 0 (1KB contiguous per load)
    #pragma unroll
    for (int j = 0; j < 8; ++j)
        GLOAD_LDS16(gp0 + j * 512, lp0 + j * 1024);

    for (int kc = 0; kc < 8; ++kc) {
        const int cur = kc & 1;
        __syncthreads();   // drains DMA for buf[cur]; prev reads of buf[cur^1] done
        if (kc + 1 < 8) {
            const ushort* gp = gp0 + (size_t)(kc + 1) * HW * 32;
            char* lp = lp0 + (cur ^ 1) * 65536;
            #pragma unroll
            for (int j = 0; j < 8; ++j)
                GLOAD_LDS16(gp + j * 512, lp + j * 1024);
        }
        const char* qb = pool + cur * 65536 + (b * 128) * 64;
        const char* kb = pool + cur * 65536 + 32768 + (b * 128) * 64;
        bf16x8 af[4];
        #pragma unroll
        for (int nf = 0; nf < 4; ++nf) {
            int row = nh * 64 + nf * 16 + l15;
            af[nf] = *(const bf16x8*)(qb + row * 64 + rsw);
        }
        #pragma unroll
        for (int mf = 0; mf < 8; ++mf) {
            int row = mf * 16 + l15;
            bf16x8 bb = *(const bf16x8*)(kb + row * 64 + rsw);
            #pragma unroll
            for (int nf = 0; nf < 4; ++nf)
                acc[nf][mf] = __builtin_amdgcn_mfma_f32_16x16x32_bf16(
                    af[nf], bb, acc[nf][mf], 0, 0, 0);
        }
    }

    // ---- epilogue: exchange scores via LDS, softmax over batch, max over n ----
    // 4 steps of 32 m-cols. SC[4b][32m][132n] f32 (67.6 KiB), red at +98304.
    float* SC  = (float*)pool;
    float* red = (float*)(pool + 98304);
    #pragma unroll
    for (int s = 0; s < 4; ++s) {
        __syncthreads();   // prev step's reads (or k-loop reads) done
        #pragma unroll
        for (int mp = 0; mp < 2; ++mp) {
            const int mc = mp * 16 + l15;
            #pragma unroll
            for (int nf = 0; nf < 4; ++nf) {
                const int n = nh * 64 + nf * 16 + (lane >> 4) * 4;
                f32x4 st = acc[nf][2 * s + mp] * 0.0625f;   // 1/sqrt(C)
                *(f32x4*)&SC[(b * 32 + mc) * 132 + n] = st;
            }
        }
        __syncthreads();
        {
            const int ml = lane & 31;               // m col within step
            const int nsub = w * 2 + (lane >> 5);   // 16 groups of 8 n
            float pm[4] = {0.f, 0.f, 0.f, 0.f};
            #pragma unroll
            for (int q = 0; q < 2; ++q) {
                f32x4 sv[4];
                #pragma unroll
                for (int b2 = 0; b2 < 4; ++b2)
                    sv[b2] = *(const f32x4*)&SC[(b2 * 32 + ml) * 132 + nsub * 8 + q * 4];
                #pragma unroll
                for (int j = 0; j < 4; ++j) {
                    float s0 = sv[0][j], s1 = sv[1][j], s2 = sv[2][j], s3 = sv[3][j];
                    float mx = fmaxf(fmaxf(s0, s1), fmaxf(s2, s3));
                    float e0 = __expf(s0 - mx), e1 = __expf(s1 - mx);
                    float e2 = __expf(s2 - mx), e3 = __expf(s3 - mx);
                    float inv = 1.0f / (e0 + e1 + e2 + e3);
                    pm[0] = fmaxf(pm[0], e0 * inv); pm[1] = fmaxf(pm[1], e1 * inv);
                    pm[2] = fmaxf(pm[2], e2 * inv); pm[3] = fmaxf(pm[3], e3 * inv);
                }
            }
            #pragma unroll
            for (int b2 = 0; b2 < 4; ++b2)
                pm[b2] = fmaxf(pm[b2], __shfl_xor(pm[b2], 32));
            if (lane < 32) {
                #pragma unroll
                for (int b2 = 0; b2 < 4; ++b2)
                    red[(w * 4 + b2) * 32 + ml] = pm[b2];
            }
        }
        __syncthreads();
        if (t < 128) {
            const int b2 = t >> 5, mc = t & 31;
            float v = red[b2 * 32 + mc];
            #pragma unroll
            for (int w2 = 1; w2 < 8; ++w2)
                v = fmaxf(v, red[(w2 * 4 + b2) * 32 + mc]);
            atomicMax(&M1[b2 * HW + m0 + s * 32 + mc], __float_as_uint(v));
        }
    }
}

// ---------------------------------------------------------------------------
extern "C" void kernel_launch(void* const* d_in, const int* in_sizes, int n_in,
                              void* d_out, int out_size, void* d_ws, size_t ws_size,
                              hipStream_t stream) {
    const float* fuse = (const float*)d_in[0];
    const float* Wq   = (const float*)d_in[1];
    const float* bq   = (const float*)d_in[2];
    const float* Wk   = (const float*)d_in[3];
    const float* bk   = (const float*)d_in[4];
    const float* Wv   = (const float*)d_in[5];
    const float* bv   = (const float*)d_in[6];
    float* out = (float*)d_out;

    char* ws = (char*)d_ws;
    ushort* fT    = (ushort*)(ws);                            // 8 MiB
    ushort* Wq16  = (ushort*)(ws + 8388608);                  // 128 KiB
    ushort* Wk16  = (ushort*)(ws + 8388608 + 131072);         // 128 KiB
    ushort* Wv16  = (ushort*)(ws + 8388608 + 262144);         // 128 KiB
    ushort* Qw    = (ushort*)(ws + 8388608 + 393216);         // 8 MiB (blocked)
    ushort* Kw    = (ushort*)(ws + 16777216 + 393216);        // 8 MiB (blocked)
    float*  Qmask = (float*) (ws + 25165824 + 393216);        // 64 KiB
    unsigned int* M1 = (unsigned int*)(ws + 25165824 + 458752); // 64 KiB

    prep_kernel<<<256, 256, 0, stream>>>(Wq, Wk, Wv, Wq16, Wk16, Wv16, M1);
    transpose_kernel<<<dim3(64, 8, NB), 256, 0, stream>>>(fuse, fT);
    conv_gemm_kernel<0><<<dim3(64, NB), 256, 0, stream>>>(
        fT, Wq16, bq, Qw, nullptr, nullptr, nullptr);
    conv_gemm_kernel<0><<<dim3(64, NB), 256, 0, stream>>>(
        fT, Wk16, bk, Kw, nullptr, nullptr, nullptr);
    qmask_kernel<<<512, 256, 0, stream>>>(Qw, Qmask);
    scores_kernel<<<dim3(32, 32), 512, 0, stream>>>(Qw, Kw, M1);
    conv_gemm_kernel<1><<<dim3(64, NB), 256, 0, stream>>>(
        fT, Wv16, bv, nullptr, out, (const float*)M1, Qmask);
}

// Round 4
// 125.281 us; speedup vs baseline: 1.1762x; 1.0374x over previous
//
#include <hip/hip_runtime.h>
#include <stdint.h>

#define HW 4096
#define CH 256
#define NB 4

typedef __attribute__((ext_vector_type(8))) short bf16x8;
typedef __attribute__((ext_vector_type(4))) float f32x4;

__device__ __forceinline__ ushort f2bf(float f) {
    uint32_t u = __float_as_uint(f);
    u += 0x7fffu + ((u >> 16) & 1u);   // RNE
    return (ushort)(u >> 16);
}
__device__ __forceinline__ float bf2f(ushort h) {
    return __uint_as_float(((uint32_t)h) << 16);
}

#define GLOAD_LDS16(g, l) __builtin_amdgcn_global_load_lds(                    \
    (const __attribute__((address_space(1))) uint32_t*)(g),                    \
    (__attribute__((address_space(3))) uint32_t*)(l), 16, 0, 0)

// ---------------------------------------------------------------------------
// prep: convert 3 weight matrices fp32->bf16, zero M1 accumulator
__global__ __launch_bounds__(256) void prep_kernel(
    const float* __restrict__ Wq, const float* __restrict__ Wk,
    const float* __restrict__ Wv,
    ushort* __restrict__ Wq16, ushort* __restrict__ Wk16,
    ushort* __restrict__ Wv16, unsigned int* __restrict__ M1) {
    int i = blockIdx.x * 256 + threadIdx.x;   // grid covers 65536
    Wq16[i] = f2bf(Wq[i]);
    Wk16[i] = f2bf(Wk[i]);
    Wv16[i] = f2bf(Wv[i]);
    if (i < NB * HW) M1[i] = 0;               // soft > 0, so 0 == -inf here
}

// ---------------------------------------------------------------------------
// transpose + convert: fuse[b][c][hw] f32 -> fT[b][hw][c] bf16
__global__ __launch_bounds__(256) void transpose_kernel(
    const float* __restrict__ fuse, ushort* __restrict__ fT) {
    __shared__ float tile[32][65];
    const int b = blockIdx.z, c0 = blockIdx.y * 32, hw0 = blockIdx.x * 64;
    const int t = threadIdx.x;
    {
        const int i0 = t >> 4;
        const int j4 = (t & 15) * 4;
        const float* src = fuse + ((size_t)b * CH + c0) * HW + hw0;
        #pragma unroll
        for (int ii = 0; ii < 2; ++ii) {
            int i = i0 + ii * 16;
            float4 v = *(const float4*)(src + (size_t)i * HW + j4);
            tile[i][j4 + 0] = v.x; tile[i][j4 + 1] = v.y;
            tile[i][j4 + 2] = v.z; tile[i][j4 + 3] = v.w;
        }
    }
    __syncthreads();
    {
        const int j = t >> 2;
        const int i8 = (t & 3) * 8;
        __align__(16) ushort o8[8];
        #pragma unroll
        for (int k = 0; k < 8; ++k) o8[k] = f2bf(tile[i8 + k][j]);
        *(int4*)(fT + ((size_t)b * HW + hw0 + j) * CH + c0 + i8) = *(const int4*)o8;
    }
}

// ---------------------------------------------------------------------------
// conv1x1 GEMM: rows = out-channel o (A = W16[o][c]), cols = hw (B = fT[hw][c])
// MODE 0: write bf16 CHANNEL-BLOCKED [b][o>>5][hw][o&31] (Q or K).
// MODE 1: V + mask epilogue (m2 computed in-kernel from M1) -> f32 out.
template<int MODE>
__global__ __launch_bounds__(256) void conv_gemm_kernel(
    const ushort* __restrict__ fT, const ushort* __restrict__ W16,
    const float* __restrict__ bias,
    ushort* __restrict__ outb, float* __restrict__ outf,
    const float* __restrict__ M1f, const float* __restrict__ qmask) {
    __shared__ __align__(16) ushort Als[256][72];
    __shared__ __align__(16) ushort Bls[64][72];
    __shared__ float m2s[64];
    const int t = threadIdx.x;
    const int lane = t & 63, w = t >> 6;
    const int hw0 = blockIdx.x * 64;
    const int b = blockIdx.y;
    if (MODE == 1) {   // fold m2: m2s[hk] = max over wk of M1[b][hk*64+wk]
        const int hk = t >> 2, q = t & 3;
        const float* rp = M1f + b * HW + hk * 64 + q * 16;
        float mx = 0.f;
        #pragma unroll
        for (int k2 = 0; k2 < 16; k2 += 4) {
            float4 v = *(const float4*)(rp + k2);
            mx = fmaxf(mx, fmaxf(fmaxf(v.x, v.y), fmaxf(v.z, v.w)));
        }
        mx = fmaxf(mx, __shfl_xor(mx, 1));
        mx = fmaxf(mx, __shfl_xor(mx, 2));
        if (q == 0) m2s[hk] = mx;
    }
    f32x4 acc[4][4] = {};   // [rf(o)][cf(hw)]
    for (int kc = 0; kc < 4; ++kc) {
        __syncthreads();
        #pragma unroll
        for (int i = 0; i < 8; ++i) {
            int q = t + 256 * i;
            int row = q >> 3, c8 = (q & 7) * 8;
            *(int4*)&Als[row][c8] =
                *(const int4*)(W16 + (size_t)row * CH + kc * 64 + c8);
        }
        #pragma unroll
        for (int i = 0; i < 2; ++i) {
            int q = t + 256 * i;
            int row = q >> 3, c8 = (q & 7) * 8;
            *(int4*)&Bls[row][c8] =
                *(const int4*)(fT + ((size_t)b * HW + hw0 + row) * CH + kc * 64 + c8);
        }
        __syncthreads();
        #pragma unroll
        for (int kk = 0; kk < 2; ++kk) {
            bf16x8 af[4];
            #pragma unroll
            for (int rf = 0; rf < 4; ++rf)
                af[rf] = *(const bf16x8*)&Als[w * 64 + rf * 16 + (lane & 15)]
                                             [kk * 32 + (lane >> 4) * 8];
            #pragma unroll
            for (int cf = 0; cf < 4; ++cf) {
                bf16x8 bf_ = *(const bf16x8*)&Bls[cf * 16 + (lane & 15)]
                                                 [kk * 32 + (lane >> 4) * 8];
                #pragma unroll
                for (int rf = 0; rf < 4; ++rf)
                    acc[rf][cf] = __builtin_amdgcn_mfma_f32_16x16x32_bf16(
                        af[rf], bf_, acc[rf][cf], 0, 0, 0);
            }
        }
    }
    #pragma unroll
    for (int rf = 0; rf < 4; ++rf) {
        const int ob = w * 64 + rf * 16 + (lane >> 4) * 4;  // o base (mult of 4)
        #pragma unroll
        for (int cf = 0; cf < 4; ++cf) {
            const int hw = hw0 + cf * 16 + (lane & 15);
            if (MODE == 0) {
                ushort4 v;
                v.x = f2bf(acc[rf][cf][0] + bias[ob + 0]);
                v.y = f2bf(acc[rf][cf][1] + bias[ob + 1]);
                v.z = f2bf(acc[rf][cf][2] + bias[ob + 2]);
                v.w = f2bf(acc[rf][cf][3] + bias[ob + 3]);
                // channel-blocked: [b][ob>>5][hw][ob&31]
                *(ushort4*)&outb[(((size_t)b * 8 + (ob >> 5)) * HW + hw) * 32
                                 + (ob & 31)] = v;
            } else {
                const float mv = m2s[ob >> 2];
                #pragma unroll
                for (int r = 0; r < 4; ++r) {   // o = ob+r, o%4 == r
                    float vv = acc[rf][cf][r] + bias[ob + r];
                    float qm = qmask[r * HW + hw];
                    outf[((size_t)b * CH + ob + r) * HW + hw] = vv * (1.0f + mv * qm);
                }
            }
        }
    }
}

// ---------------------------------------------------------------------------
// Q_mask[(c%4)*HW + hw] = max over b, c/4 of Q[b][c][hw]; Q channel-blocked.
__global__ __launch_bounds__(256) void qmask_kernel(
    const ushort* __restrict__ Qw, float* __restrict__ Qmask) {
    const int t = threadIdx.x;
    const int j = t >> 5;        // 8 hw rows per block
    const int l5 = t & 31;
    const int hw = blockIdx.x * 8 + j;
    float mx = -3.4e38f;
    for (int b = 0; b < 4; ++b) {
        #pragma unroll
        for (int k = 0; k < 8; ++k) {   // c = k*32 + l5; c&3 == l5&3
            ushort u = Qw[(((size_t)b * 8 + k) * HW + hw) * 32 + l5];
            mx = fmaxf(mx, bf2f(u));
        }
    }
    // reduce within 32-lane group over c bits 2..4 (keeps class c%4 == l5&3)
    mx = fmaxf(mx, __shfl_xor(mx, 4));
    mx = fmaxf(mx, __shfl_xor(mx, 8));
    mx = fmaxf(mx, __shfl_xor(mx, 16));
    if (l5 < 4) Qmask[l5 * HW + hw] = mx;
}

// ---------------------------------------------------------------------------
// scores + batch-softmax + max-over-n reduction.
// 512 threads = 8 waves: wave w -> (batch b = w&3, n-half nh = w>>2).
// Block tile: 128n x 128m, per-wave 64n x 128m of ONE batch (nf=4 x mf=8).
// Staging: global_load_lds 16B from channel-blocked [b][kc][hw][32] layout.
// K-loop sync: raw s_barrier + COUNTED vmcnt (T3/T4) -- depth-2 prefetch
// streams across barriers; no vmcnt(0) drain until the last chunk.
__global__ __launch_bounds__(512, 2) void scores_kernel(
    const ushort* __restrict__ Qw, const ushort* __restrict__ Kw,
    unsigned int* __restrict__ M1) {
    __shared__ __align__(16) char pool[131072];   // 2 x (Q 32K + K 32K); epilogue reuse
    const int t = threadIdx.x;
    const int lane = t & 63, w = t >> 6;
    const int b = w & 3, nh = w >> 2;
    // bijective XCD-clustered swizzle of the 32x32 tile grid
    const int id = blockIdx.y * 32 + blockIdx.x;
    const int xcd = id & 7, jj = id >> 3, wg = jj >> 5, r = jj & 31;
    const int vn = xcd * 4 + (r & 3), vm = wg * 8 + (r >> 2);
    const int m0 = vm * 128, n0 = vn * 128;

    // staging role: wave w stages tile (w>>2): 0=Q rows, 1=K rows, batch w&3
    const int tile = w >> 2, wb = w & 3;
    const ushort* Src = tile ? Kw : Qw;
    const int base0 = tile ? m0 : n0;
    const int sub = (lane & 3) ^ ((lane >> 3) & 3);  // 16B slot permutation
    const ushort* gp0 = Src + ((size_t)(wb * 8) * HW + base0 + (lane >> 2)) * 32
                        + sub * 8;
    char* lp0 = pool + (tile * 512 + wb * 128) * 64;

    // read-side swizzled chunk byte offset (same for every fragment row)
    const int rsw = (((lane >> 4) ^ ((lane >> 1) & 3)) << 4);
    const int l15 = lane & 15;

    f32x4 acc[4][8] = {};   // [nf][mf]

    // prologue: stage chunks 0,1 (depth-2; 16 loads outstanding per wave)
    #pragma unroll
    for (int j = 0; j < 8; ++j)
        GLOAD_LDS16(gp0 + j * 512, lp0 + j * 1024);
    #pragma unroll
    for (int j = 0; j < 8; ++j)
        GLOAD_LDS16(gp0 + (size_t)HW * 32 + j * 512, lp0 + 65536 + j * 1024);

    #pragma unroll
    for (int kc = 0; kc < 8; ++kc) {
        const int cur = kc & 1;
        // counted wait: oldest 8 outstanding = chunk kc's loads
        if (kc == 7) asm volatile("s_waitcnt vmcnt(0)" ::: "memory");
        else         asm volatile("s_waitcnt vmcnt(8)" ::: "memory");
        asm volatile("s_barrier" ::: "memory");   // union of per-wave regions ready

        const char* qb = pool + cur * 65536 + (b * 128) * 64;
        const char* kb = pool + cur * 65536 + 32768 + (b * 128) * 64;
        bf16x8 af[4];
        #pragma unroll
        for (int nf = 0; nf < 4; ++nf) {
            int row = nh * 64 + nf * 16 + l15;
            af[nf] = *(const bf16x8*)(qb + row * 64 + rsw);
        }
        #pragma unroll
        for (int mf = 0; mf < 8; ++mf) {
            int row = mf * 16 + l15;
            bf16x8 bb = *(const bf16x8*)(kb + row * 64 + rsw);
            #pragma unroll
            for (int nf = 0; nf < 4; ++nf)
                acc[nf][mf] = __builtin_amdgcn_mfma_f32_16x16x32_bf16(
                    af[nf], bb, acc[nf][mf], 0, 0, 0);
        }

        // all my LDS reads serviced -> safe for others to overwrite after barrier
        asm volatile("s_waitcnt lgkmcnt(0)" ::: "memory");
        __builtin_amdgcn_sched_barrier(0);
        asm volatile("s_barrier" ::: "memory");
        if (kc + 2 < 8) {
            const ushort* gp = gp0 + (size_t)(kc + 2) * HW * 32;
            char* lp = lp0 + cur * 65536;   // buffer just consumed
            #pragma unroll
            for (int j = 0; j < 8; ++j)
                GLOAD_LDS16(gp + j * 512, lp + j * 1024);
        }
    }

    // ---- epilogue: exchange scores via LDS, softmax over batch, max over n ----
    // 4 steps of 32 m-cols. SC[4b][32m][132n] f32 (67.6 KiB), red at +98304.
    float* SC  = (float*)pool;
    float* red = (float*)(pool + 98304);
    #pragma unroll
    for (int s = 0; s < 4; ++s) {
        __syncthreads();   // prev step's reads (or k-loop reads) done
        #pragma unroll
        for (int mp = 0; mp < 2; ++mp) {
            const int mc = mp * 16 + l15;
            #pragma unroll
            for (int nf = 0; nf < 4; ++nf) {
                const int n = nh * 64 + nf * 16 + (lane >> 4) * 4;
                f32x4 st = acc[nf][2 * s + mp] * 0.0625f;   // 1/sqrt(C)
                *(f32x4*)&SC[(b * 32 + mc) * 132 + n] = st;
            }
        }
        __syncthreads();
        {
            const int ml = lane & 31;               // m col within step
            const int nsub = w * 2 + (lane >> 5);   // 16 groups of 8 n
            float pm[4] = {0.f, 0.f, 0.f, 0.f};
            #pragma unroll
            for (int q = 0; q < 2; ++q) {
                f32x4 sv[4];
                #pragma unroll
                for (int b2 = 0; b2 < 4; ++b2)
                    sv[b2] = *(const f32x4*)&SC[(b2 * 32 + ml) * 132 + nsub * 8 + q * 4];
                #pragma unroll
                for (int j = 0; j < 4; ++j) {
                    float s0 = sv[0][j], s1 = sv[1][j], s2 = sv[2][j], s3 = sv[3][j];
                    float mx = fmaxf(fmaxf(s0, s1), fmaxf(s2, s3));
                    float e0 = __expf(s0 - mx), e1 = __expf(s1 - mx);
                    float e2 = __expf(s2 - mx), e3 = __expf(s3 - mx);
                    float inv = 1.0f / (e0 + e1 + e2 + e3);
                    pm[0] = fmaxf(pm[0], e0 * inv); pm[1] = fmaxf(pm[1], e1 * inv);
                    pm[2] = fmaxf(pm[2], e2 * inv); pm[3] = fmaxf(pm[3], e3 * inv);
                }
            }
            #pragma unroll
            for (int b2 = 0; b2 < 4; ++b2)
                pm[b2] = fmaxf(pm[b2], __shfl_xor(pm[b2], 32));
            if (lane < 32) {
                #pragma unroll
                for (int b2 = 0; b2 < 4; ++b2)
                    red[(w * 4 + b2) * 32 + ml] = pm[b2];
            }
        }
        __syncthreads();
        if (t < 128) {
            const int b2 = t >> 5, mc = t & 31;
            float v = red[b2 * 32 + mc];
            #pragma unroll
            for (int w2 = 1; w2 < 8; ++w2)
                v = fmaxf(v, red[(w2 * 4 + b2) * 32 + mc]);
            atomicMax(&M1[b2 * HW + m0 + s * 32 + mc], __float_as_uint(v));
        }
    }
}

// ---------------------------------------------------------------------------
extern "C" void kernel_launch(void* const* d_in, const int* in_sizes, int n_in,
                              void* d_out, int out_size, void* d_ws, size_t ws_size,
                              hipStream_t stream) {
    const float* fuse = (const float*)d_in[0];
    const float* Wq   = (const float*)d_in[1];
    const float* bq   = (const float*)d_in[2];
    const float* Wk   = (const float*)d_in[3];
    const float* bk   = (const float*)d_in[4];
    const float* Wv   = (const float*)d_in[5];
    const float* bv   = (const float*)d_in[6];
    float* out = (float*)d_out;

    char* ws = (char*)d_ws;
    ushort* fT    = (ushort*)(ws);                            // 8 MiB
    ushort* Wq16  = (ushort*)(ws + 8388608);                  // 128 KiB
    ushort* Wk16  = (ushort*)(ws + 8388608 + 131072);         // 128 KiB
    ushort* Wv16  = (ushort*)(ws + 8388608 + 262144);         // 128 KiB
    ushort* Qw    = (ushort*)(ws + 8388608 + 393216);         // 8 MiB (blocked)
    ushort* Kw    = (ushort*)(ws + 16777216 + 393216);        // 8 MiB (blocked)
    float*  Qmask = (float*) (ws + 25165824 + 393216);        // 64 KiB
    unsigned int* M1 = (unsigned int*)(ws + 25165824 + 458752); // 64 KiB

    prep_kernel<<<256, 256, 0, stream>>>(Wq, Wk, Wv, Wq16, Wk16, Wv16, M1);
    transpose_kernel<<<dim3(64, 8, NB), 256, 0, stream>>>(fuse, fT);
    conv_gemm_kernel<0><<<dim3(64, NB), 256, 0, stream>>>(
        fT, Wq16, bq, Qw, nullptr, nullptr, nullptr);
    conv_gemm_kernel<0><<<dim3(64, NB), 256, 0, stream>>>(
        fT, Wk16, bk, Kw, nullptr, nullptr, nullptr);
    qmask_kernel<<<512, 256, 0, stream>>>(Qw, Qmask);
    scores_kernel<<<dim3(32, 32), 512, 0, stream>>>(Qw, Kw, M1);
    conv_gemm_kernel<1><<<dim3(64, NB), 256, 0, stream>>>(
        fT, Wv16, bv, nullptr, out, (const float*)M1, Qmask);
}